// Round 1
// 385.420 us; speedup vs baseline: 1.4069x; 1.4069x over previous
//
#include <hip/hip_runtime.h>

// Problem constants
constexpr int Bn = 32, Ln = 1855, Kn = 7, Tn = 40, CIn = 8, COn = 32, TKSn = 5, TOn = 36;
constexpr int BG   = 8;               // b per block
constexpr int KRED = Kn * TKSn * CIn; // 280
constexpr int KPAD = 288;             // padded K (9 chunks of 32), [280,288) zero
constexpr int WROW = 296;             // fallback kernel's padded wt row
constexpr int XS_ELEMS = BG * Kn * Tn * CIn; // 17920 bf16
constexpr size_t XN = (size_t)Bn * Ln * Tn * CIn; // 18,995,200 elems

// workspace layout (bytes)
constexpr size_t WS_WT   = 0;                 // 32*288 bf16 = 18432 B
constexpr size_t WS_ZPAD = 18432;             // 128 B of zeros (masked-gather target)
constexpr size_t WS_XBF  = 18560;             // XN bf16 = 37,990,400 B
constexpr size_t WS_NEED = WS_XBF + XN * 2;

typedef __attribute__((ext_vector_type(8))) short bf16x8;          // 8 bf16 = 4 VGPRs
typedef __attribute__((ext_vector_type(8))) unsigned short u16x8;
typedef __attribute__((ext_vector_type(4))) float f32x4;           // MFMA C/D

__device__ inline unsigned short f2bf(float f) {
    unsigned u = __builtin_bit_cast(unsigned, f);
    u += 0x7fffu + ((u >> 16) & 1u); // RNE
    return (unsigned short)(u >> 16);
}

__device__ inline void gload_lds16(const void* g, void* lds) {
    __builtin_amdgcn_global_load_lds(
        (const __attribute__((address_space(1))) unsigned int*)g,
        (__attribute__((address_space(3))) unsigned int*)lds,
        16, 0, 0);
}

// ---- prep kernels (run once per launch, tiny) ----

// w (K,TKS,CIn,COn) fp32 -> wt[o][kred] bf16, row padded to 288 with zeros.
__global__ __launch_bounds__(256) void prep_w(const float* __restrict__ w,
                                              unsigned short* __restrict__ wt,
                                              unsigned short* __restrict__ zpad) {
    const int tid = threadIdx.x;
    for (int p = tid; p < KRED * COn; p += 256) { // 8960
        int o  = p & 31;
        int kr = p >> 5;                          // (k*5+tau)*8+i
        wt[o * KPAD + kr] = f2bf(w[p]);
    }
    for (int p = tid; p < COn * (KPAD - KRED); p += 256) { // 256
        int o = p >> 3;
        wt[o * KPAD + KRED + (p & 7)] = 0;
    }
    if (tid < 64) zpad[tid] = 0; // 128 B zeros
}

// x fp32 -> bf16, same (B,L,T,CIn) layout. 16B loads x2 -> 16B store.
__global__ __launch_bounds__(256) void prep_x(const float* __restrict__ x,
                                              unsigned short* __restrict__ xbf) {
    const size_t n8 = XN / 8; // 2,374,400 groups of 8
    for (size_t p = (size_t)blockIdx.x * 256 + threadIdx.x; p < n8;
         p += (size_t)gridDim.x * 256) {
        float4 a = ((const float4*)x)[2 * p];
        float4 b = ((const float4*)x)[2 * p + 1];
        u16x8 v;
        v[0] = f2bf(a.x); v[1] = f2bf(a.y); v[2] = f2bf(a.z); v[3] = f2bf(a.w);
        v[4] = f2bf(b.x); v[5] = f2bf(b.y); v[6] = f2bf(b.z); v[7] = f2bf(b.w);
        *(u16x8*)&xbf[p * 8] = v;
    }
}

// ---- main kernel: bf16 x, global wt, async gather, 36KB LDS (4 blocks/CU) ----
__global__ __launch_bounds__(256, 4) void conv_mfma2(
    const unsigned short* __restrict__ xbf,  // (B, L, T, CIn) bf16
    const int*   __restrict__ nbr,           // (L, K)
    const unsigned short* __restrict__ wt,   // [32][288] bf16
    const unsigned short* __restrict__ zpad, // 128B zeros
    const float* __restrict__ bias,          // (COn,)
    float*       __restrict__ out)           // (B, L, TOn, COn)
{
    // xs: gathered neighbor rows, bf16, layout [b_local][k][t][i], i contiguous.
    // +8 zero pad row used as the A-source for the padded K chunk (quad==3, c==8).
    __shared__ unsigned short xs[XS_ELEMS + 8]; // 35,856 B — only LDS user now

    const int tid  = threadIdx.x;
    const int l    = blockIdx.x;
    const int bg   = blockIdx.y;
    const int wave = tid >> 6;
    const int lane = tid & 63;

    if (tid < 8) xs[XS_ELEMS + tid] = 0; // zero A-pad row

    // ---- stage gathered x via async global->LDS, 35 wave-chunks of 1024B ----
    // chunk ch covers ushort8 indices [ch*64, ch*64+64); LDS dest is linear
    // (wave-uniform base + lane*16), per-lane global src handles the scatter.
    for (int ch = wave; ch < 35; ch += 4) {
        int p   = ch * 64 + lane;        // [0, 2240) ushort8 units
        int row = p / 40;                // (b_local, k) row, 40 ushort8 each
        int q   = p - row * 40;          // t index
        int b_local = row / 7;
        int k       = row - b_local * 7;
        int l2 = nbr[l * Kn + k];
        const unsigned short* src = zpad;
        if (l2 >= 0)
            src = xbf + ((size_t)(bg * BG + b_local) * Ln + l2) * 320 + q * 8;
        gload_lds16(src, &xs[ch * 512]);
    }

    // ---- B fragments straight from global (18KB, L2-broadcast) ----
    const int quad = lane >> 4;
    const int lrow = lane & 15;
    const int o_base  = (wave & 1) * 16;  // o col-tile
    const int rt_base = (wave >> 1) * 9;  // 9 row-tiles of 16 per wave

    bf16x8 bfrag[9];
    const unsigned short* wrow = wt + (o_base + lrow) * KPAD;
    #pragma unroll
    for (int c = 0; c < 9; ++c)
        bfrag[c] = *(const bf16x8*)(wrow + c * 32 + quad * 8);
    const float bv = bias[o_base + lrow];

    __syncthreads(); // implicit vmcnt(0): staging + bfrag loads complete

    // ---- MFMA compute: rows m = b_local*36 + t (288), cols o (32), K 288 ----
    #pragma unroll
    for (int g = 0; g < 3; ++g) {       // 3 groups x 3 row-tiles (ILP)
        const int rt0 = rt_base + g * 3;
        f32x4 acc0 = {0.f,0.f,0.f,0.f}, acc1 = acc0, acc2 = acc0;
        const int m0 = (rt0 + 0) * 16 + lrow;
        const int m1 = (rt0 + 1) * 16 + lrow;
        const int m2 = (rt0 + 2) * 16 + lrow;
        const int bl0 = m0 / 36, t0 = m0 - bl0 * 36;
        const int bl1 = m1 / 36, t1 = m1 - bl1 * 36;
        const int bl2 = m2 / 36, t2 = m2 - bl2 * 36;
        const int base0 = bl0 * 2240 + t0 * 8;
        const int base1 = bl1 * 2240 + t1 * 8;
        const int base2 = bl2 * 2240 + t2 * 8;
        #pragma unroll
        for (int c = 0; c < 9; ++c) {
            const int p = c * 4 + quad;         // (k,tau) pair index, 36th is pad
            const int knbr = p / 5, tau = p - knbr * 5;
            const int koff = knbr * 320 + tau * 8;
            int o0 = base0 + koff, o1 = base1 + koff, o2 = base2 + koff;
            if (c == 8 && quad == 3) { o0 = XS_ELEMS; o1 = XS_ELEMS; o2 = XS_ELEMS; }
            bf16x8 a0 = *(const bf16x8*)&xs[o0];
            bf16x8 a1 = *(const bf16x8*)&xs[o1];
            bf16x8 a2 = *(const bf16x8*)&xs[o2];
            acc0 = __builtin_amdgcn_mfma_f32_16x16x32_bf16(a0, bfrag[c], acc0, 0, 0, 0);
            acc1 = __builtin_amdgcn_mfma_f32_16x16x32_bf16(a1, bfrag[c], acc1, 0, 0, 0);
            acc2 = __builtin_amdgcn_mfma_f32_16x16x32_bf16(a2, bfrag[c], acc2, 0, 0, 0);
        }
        // epilogue: C/D layout col=lane&15, row=quad*4+reg  [m89/m91 verified]
        #pragma unroll
        for (int i = 0; i < 3; ++i) {
            const f32x4 acc = (i == 0) ? acc0 : ((i == 1) ? acc1 : acc2);
            const int rt = rt0 + i;
            #pragma unroll
            for (int reg = 0; reg < 4; ++reg) {
                const int m  = rt * 16 + quad * 4 + reg;
                const int bl = m / 36, t = m - bl * 36;
                const size_t off =
                    (((size_t)(bg * BG + bl) * Ln + l) * TOn + t) * COn + o_base + lrow;
                out[off] = acc[reg] + bv;
            }
        }
    }
}

// ---- fallback (original kernel) if workspace is too small ----
__global__ __launch_bounds__(256) void conv_mfma(
    const float* __restrict__ x, const int* __restrict__ nbr,
    const float* __restrict__ w, const float* __restrict__ bias,
    float* __restrict__ out)
{
    __shared__ unsigned short xs[XS_ELEMS + 8];
    __shared__ unsigned short wt[COn * WROW];

    const int tid = threadIdx.x;
    const int l   = blockIdx.x;
    const int bg  = blockIdx.y;

    for (int p = tid; p < KRED * COn; p += 256) {
        int o  = p & 31;
        int kr = p >> 5;
        wt[o * WROW + kr] = f2bf(w[p]);
    }
    for (int p = tid; p < COn * (WROW - KRED); p += 256) {
        int o = p >> 4;
        wt[o * WROW + KRED + (p & 15)] = 0;
    }
    if (tid < 8) xs[XS_ELEMS + tid] = 0;

    for (int p = tid; p < BG * Kn * 80; p += 256) {
        int b_local = p / 560;
        int r = p - b_local * 560;
        int k = r / 80;
        int q = r - k * 80;
        int l2 = nbr[l * Kn + k];
        float4 v = make_float4(0.f, 0.f, 0.f, 0.f);
        if (l2 >= 0)
            v = ((const float4*)x)[((size_t)(bg * BG + b_local) * Ln + l2) * 80 + q];
        ushort4 pk;
        pk.x = f2bf(v.x); pk.y = f2bf(v.y); pk.z = f2bf(v.z); pk.w = f2bf(v.w);
        *(ushort4*)&xs[p * 4] = pk;
    }
    __syncthreads();

    const int wave = tid >> 6;
    const int lane = tid & 63;
    const int quad = lane >> 4;
    const int lrow = lane & 15;
    const int o_base  = (wave & 1) * 16;
    const int rt_base = (wave >> 1) * 9;

    bf16x8 bfrag[9];
    #pragma unroll
    for (int c = 0; c < 9; ++c)
        bfrag[c] = *(const bf16x8*)&wt[(o_base + lrow) * WROW + c * 32 + quad * 8];

    const float bv = bias[o_base + lrow];

    #pragma unroll
    for (int g = 0; g < 3; ++g) {
        const int rt0 = rt_base + g * 3;
        f32x4 acc0 = {0.f,0.f,0.f,0.f}, acc1 = acc0, acc2 = acc0;
        const int m0 = (rt0 + 0) * 16 + lrow;
        const int m1 = (rt0 + 1) * 16 + lrow;
        const int m2 = (rt0 + 2) * 16 + lrow;
        const int bl0 = m0 / 36, t0 = m0 - bl0 * 36;
        const int bl1 = m1 / 36, t1 = m1 - bl1 * 36;
        const int bl2 = m2 / 36, t2 = m2 - bl2 * 36;
        const int base0 = bl0 * 2240 + t0 * 8;
        const int base1 = bl1 * 2240 + t1 * 8;
        const int base2 = bl2 * 2240 + t2 * 8;
        #pragma unroll
        for (int c = 0; c < 9; ++c) {
            const int p = c * 4 + quad;
            const int knbr = p / 5, tau = p - knbr * 5;
            const int koff = knbr * 320 + tau * 8;
            int o0 = base0 + koff, o1 = base1 + koff, o2 = base2 + koff;
            if (c == 8 && quad == 3) { o0 = XS_ELEMS; o1 = XS_ELEMS; o2 = XS_ELEMS; }
            bf16x8 a0 = *(const bf16x8*)&xs[o0];
            bf16x8 a1 = *(const bf16x8*)&xs[o1];
            bf16x8 a2 = *(const bf16x8*)&xs[o2];
            acc0 = __builtin_amdgcn_mfma_f32_16x16x32_bf16(a0, bfrag[c], acc0, 0, 0, 0);
            acc1 = __builtin_amdgcn_mfma_f32_16x16x32_bf16(a1, bfrag[c], acc1, 0, 0, 0);
            acc2 = __builtin_amdgcn_mfma_f32_16x16x32_bf16(a2, bfrag[c], acc2, 0, 0, 0);
        }
        #pragma unroll
        for (int i = 0; i < 3; ++i) {
            const f32x4 acc = (i == 0) ? acc0 : ((i == 1) ? acc1 : acc2);
            const int rt = rt0 + i;
            #pragma unroll
            for (int reg = 0; reg < 4; ++reg) {
                const int m  = rt * 16 + quad * 4 + reg;
                const int bl = m / 36, t = m - bl * 36;
                const size_t off =
                    (((size_t)(bg * BG + bl) * Ln + l) * TOn + t) * COn + o_base + lrow;
                out[off] = acc[reg] + bv;
            }
        }
    }
}

extern "C" void kernel_launch(void* const* d_in, const int* in_sizes, int n_in,
                              void* d_out, int out_size, void* d_ws, size_t ws_size,
                              hipStream_t stream) {
    const float* x    = (const float*)d_in[0];
    const int*   nbr  = (const int*)d_in[1];
    const float* w    = (const float*)d_in[2];
    const float* bias = (const float*)d_in[3];
    float*       out  = (float*)d_out;

    dim3 grid(Ln, Bn / BG); // (1855, 4)

    if (ws_size >= WS_NEED && d_ws != nullptr) {
        unsigned short* wt   = (unsigned short*)((char*)d_ws + WS_WT);
        unsigned short* zpad = (unsigned short*)((char*)d_ws + WS_ZPAD);
        unsigned short* xbf  = (unsigned short*)((char*)d_ws + WS_XBF);
        prep_w<<<1, 256, 0, stream>>>(w, wt, zpad);
        prep_x<<<2048, 256, 0, stream>>>(x, xbf);
        conv_mfma2<<<grid, dim3(256), 0, stream>>>(xbf, nbr, wt, zpad, bias, out);
    } else {
        conv_mfma<<<grid, dim3(256), 0, stream>>>(x, nbr, w, bias, out);
    }
}